// Round 1
// baseline (135.298 us; speedup 1.0000x reference)
//
#include <hip/hip_runtime.h>
#include <math.h>

#define IMG 128
#define NPIX (IMG * IMG)
#define NF 1024
#define FSTRIDE 12  // floats per face record (3 x float4)

struct AllViews { float m[4][12]; };  // per view: xax[3], yax[3], zax[3], eye[3]

// Per (view, face): transform+project vertices, precompute edge/det data.
__global__ void precompute_faces(const float* __restrict__ verts,
                                 const int* __restrict__ faces,
                                 float* __restrict__ fd,
                                 AllViews vc, float W)
{
    int t = blockIdx.x * blockDim.x + threadIdx.x;
    if (t >= 4 * NF) return;
    int view = t >> 10, f = t & (NF - 1);
    const float* M = vc.m[view];

    float proj[3][3];
    for (int k = 0; k < 3; ++k) {
        int vi = faces[f * 3 + k];
        float px = verts[vi * 3 + 0] - M[9];
        float py = verts[vi * 3 + 1] - M[10];
        float pz = verts[vi * 3 + 2] - M[11];
        float x = M[0] * px + M[1] * py + M[2] * pz;
        float y = M[3] * px + M[4] * py + M[5] * pz;
        float z = M[6] * px + M[7] * py + M[8] * pz;
        proj[k][0] = x / (z * W);
        proj[k][1] = y / (z * W);
        proj[k][2] = z;
    }
    float v0x = proj[0][0], v0y = proj[0][1];
    float e1x = proj[1][0] - v0x, e1y = proj[1][1] - v0y;
    float e2x = proj[2][0] - v0x, e2y = proj[2][1] - v0y;
    float det = e1x * e2y - e1y * e2x;
    bool ok = fabsf(det) > 1e-8f;
    float inv = ok ? 1.0f / det : 0.0f;

    float* o = fd + (size_t)(view * NF + f) * FSTRIDE;
    o[0] = v0x;        o[1] = v0y;        o[2]  = e1x;        o[3]  = e1y;
    o[4] = e2x;        o[5] = e2y;        o[6]  = inv;        o[7]  = ok ? 1.0f : 0.0f;
    o[8] = proj[0][2]; o[9] = proj[1][2]; o[10] = proj[2][2]; o[11] = 0.0f;
}

// One thread per (view, pixel). Face data staged in LDS, broadcast reads.
__global__ __launch_bounds__(128) void render_loss(
    const float* __restrict__ fd,
    const float* __restrict__ tex,
    const float* __restrict__ refs,
    float* __restrict__ out)
{
    __shared__ float4 lds[NF * 3];
    __shared__ float wsum[2];

    int bid = blockIdx.x;
    int view = bid >> 7;       // 128 blocks per view
    int tile = bid & 127;
    int tid = threadIdx.x;

    const float4* src = (const float4*)(fd + (size_t)view * NF * FSTRIDE);
    for (int i = tid; i < NF * 3; i += 128) lds[i] = src[i];
    __syncthreads();

    int p = tile * 128 + tid;        // pixel index, row-major
    int row = p >> 7, col = p & 127;
    float sx = ((col + 0.5f) * (1.0f / IMG)) * 2.0f - 1.0f;
    float sy = -(((row + 0.5f) * (1.0f / IMG)) * 2.0f - 1.0f);

    float best = INFINITY;
    int bidx = 0;
    float bw1 = 0.0f, bw2 = 0.0f;

#pragma unroll 4
    for (int f = 0; f < NF; ++f) {
        float4 A = lds[f * 3 + 0];   // v0x v0y e1x e1y
        float4 B = lds[f * 3 + 1];   // e2x e2y inv ok
        float4 C = lds[f * 3 + 2];   // fz0 fz1 fz2 pad
        float dx = sx - A.x, dy = sy - A.y;
        float w1 = (B.y * dx - B.x * dy) * B.z;
        float w2 = (A.z * dy - A.w * dx) * B.z;
        float w0 = 1.0f - w1 - w2;
        float depth = w0 * C.x + w1 * C.y + w2 * C.z;
        bool vis = (w0 >= 0.0f) && (w1 >= 0.0f) && (w2 >= 0.0f) &&
                   (B.w != 0.0f) && (depth > 0.1f);
        bool take = vis && (depth < best);   // strict < keeps first (lowest) index
        if (take) { best = depth; bidx = f; bw1 = w1; bw2 = w2; }
    }

    float ref = refs[view * NPIX + p];
    float lossv;
    if (best < INFINITY) {
        float w0 = 1.0f - bw1 - bw2;
        float cx = fminf(fmaxf(w0, 0.0f), 1.0f) * 3.0f;
        float cy = fminf(fmaxf(bw1, 0.0f), 1.0f) * 3.0f;
        float cz = fminf(fmaxf(bw2, 0.0f), 1.0f) * 3.0f;
        int ix = min(max((int)floorf(cx), 0), 2);
        int iy = min(max((int)floorf(cy), 0), 2);
        int iz = min(max((int)floorf(cz), 0), 2);
        float fx = cx - (float)ix, fy = cy - (float)iy, fz = cz - (float)iz;

        const float* T = tex + (size_t)bidx * 192;   // 4*4*4*3
        float c0 = 0.0f, c1 = 0.0f, c2 = 0.0f;
        for (int dxi = 0; dxi < 2; ++dxi)
            for (int dyi = 0; dyi < 2; ++dyi)
                for (int dzi = 0; dzi < 2; ++dzi) {
                    float w = (dxi ? fx : 1.0f - fx) *
                              (dyi ? fy : 1.0f - fy) *
                              (dzi ? fz : 1.0f - fz);
                    int base = (((ix + dxi) * 4 + (iy + dyi)) * 4 + (iz + dzi)) * 3;
                    c0 += w * tanhf(T[base + 0]);
                    c1 += w * tanhf(T[base + 1]);
                    c2 += w * tanhf(T[base + 2]);
                }
        float d0 = c0 - ref, d1 = c1 - ref, d2 = c2 - ref;
        lossv = d0 * d0 + d1 * d1 + d2 * d2;
    } else {
        lossv = 3.0f * ref * ref;   // color == 0 for all 3 channels
    }

    // wave (64) shuffle reduce, then 2-wave LDS reduce, one atomic per block
    for (int off = 32; off; off >>= 1) lossv += __shfl_down(lossv, off);
    if ((tid & 63) == 0) wsum[tid >> 6] = lossv;
    __syncthreads();
    if (tid == 0) atomicAdd(out, wsum[0] + wsum[1]);
}

static void make_view(double dist, double elev, double azim, float* M)
{
    double e = elev * M_PI / 180.0, a = azim * M_PI / 180.0;
    float ex = (float)(dist * cos(e) * sin(a));
    float ey = (float)(dist * sin(e));
    float ez = (float)(-dist * cos(e) * cos(a));
    // z axis = normalize(-eye)
    float zx = -ex, zy = -ey, zz = -ez;
    float n = sqrtf(zx * zx + zy * zy + zz * zz);
    zx /= n; zy /= n; zz /= n;
    // x axis = normalize(cross((0,1,0), z)) = normalize((z.z, 0, -z.x))
    float xx = zz, xy = 0.0f, xz = -zx;
    n = sqrtf(xx * xx + xy * xy + xz * xz);
    xx /= n; xy /= n; xz /= n;
    // y axis = normalize(cross(z, x))
    float yx = zy * xz - zz * xy;
    float yy = zz * xx - zx * xz;
    float yz = zx * xy - zy * xx;
    n = sqrtf(yx * yx + yy * yy + yz * yz);
    yx /= n; yy /= n; yz /= n;
    M[0] = xx; M[1] = xy; M[2] = xz;
    M[3] = yx; M[4] = yy; M[5] = yz;
    M[6] = zx; M[7] = zy; M[8] = zz;
    M[9] = ex; M[10] = ey; M[11] = ez;
}

extern "C" void kernel_launch(void* const* d_in, const int* in_sizes, int n_in,
                              void* d_out, int out_size, void* d_ws, size_t ws_size,
                              hipStream_t stream)
{
    const float* verts = (const float*)d_in[0];
    const int*   faces = (const int*)d_in[1];
    const float* tex   = (const float*)d_in[2];
    const float* refs  = (const float*)d_in[3];
    float* out = (float*)d_out;
    float* fd  = (float*)d_ws;   // 4 * 1024 * 12 floats = 192 KB

    AllViews vc;
    const double V[4][3] = {{2.83, 45.0, 0.0}, {2.0, 0.0, 90.0},
                            {3.46, 45.0, 45.0}, {3.0, 0.0, 0.0}};
    for (int i = 0; i < 4; ++i) make_view(V[i][0], V[i][1], V[i][2], vc.m[i]);
    float W = (float)tan(M_PI / 6.0);

    hipMemsetAsync(d_out, 0, sizeof(float), stream);
    precompute_faces<<<16, 256, 0, stream>>>(verts, faces, fd, vc, W);
    render_loss<<<512, 128, 0, stream>>>(fd, tex, refs, out);
}

// Round 2
// 49.651 us; speedup vs baseline: 2.7250x; 2.7250x over previous
//
#include <hip/hip_runtime.h>
#include <math.h>

#define IMG 128
#define NPIX (IMG * IMG)
#define NF 1024
#define NCHUNK 8
#define CHF (NF / NCHUNK)          // 128 faces per chunk
#define FSTRIDE 12                 // floats per face record (3 x float4)
#define NEAR_Z 0.1f

struct AllViews { float m[4][12]; };  // per view: xax[3], yax[3], zax[3], eye[3]

// Per (view, face): transform+project vertices, build affine planes for
// w1, w2, depth as functions of screen (px, py).
__global__ void precompute_faces(const float* __restrict__ verts,
                                 const int* __restrict__ faces,
                                 float* __restrict__ fd,
                                 AllViews vc, float W)
{
    int t = blockIdx.x * blockDim.x + threadIdx.x;
    if (t >= 4 * NF) return;
    int view = t >> 10, f = t & (NF - 1);
    const float* M = vc.m[view];

    float proj[3][3];
    for (int k = 0; k < 3; ++k) {
        int vi = faces[f * 3 + k];
        float px = verts[vi * 3 + 0] - M[9];
        float py = verts[vi * 3 + 1] - M[10];
        float pz = verts[vi * 3 + 2] - M[11];
        float x = M[0] * px + M[1] * py + M[2] * pz;
        float y = M[3] * px + M[4] * py + M[5] * pz;
        float z = M[6] * px + M[7] * py + M[8] * pz;
        proj[k][0] = x / (z * W);
        proj[k][1] = y / (z * W);
        proj[k][2] = z;
    }
    float v0x = proj[0][0], v0y = proj[0][1];
    float e1x = proj[1][0] - v0x, e1y = proj[1][1] - v0y;
    float e2x = proj[2][0] - v0x, e2y = proj[2][1] - v0y;
    float det = e1x * e2y - e1y * e2x;
    bool ok = fabsf(det) > 1e-8f;
    float inv = ok ? 1.0f / det : 0.0f;

    // w1 = a1.p + b1 ; w2 = a2.p + b2 ; depth = dd.p + dc
    float a1x = e2y * inv, a1y = -e2x * inv;
    float b1 = -(a1x * v0x + a1y * v0y);
    float a2x = -e1y * inv, a2y = e1x * inv;
    float b2 = -(a2x * v0x + a2y * v0y);
    float g1 = proj[1][2] - proj[0][2];
    float g2 = proj[2][2] - proj[0][2];
    float ddx = g1 * a1x + g2 * a2x;
    float ddy = g1 * a1y + g2 * a2y;
    float dc  = proj[0][2] + g1 * b1 + g2 * b2;
    if (!ok) dc = 0.0f;   // depth 0 < NEAR -> never visible (matches `ok` mask)

    float* o = fd + (size_t)(view * NF + f) * FSTRIDE;
    o[0] = a1x; o[1] = a1y; o[2] = b1;  o[3] = a2x;
    o[4] = a2y; o[5] = b2;  o[6] = ddx; o[7] = ddy;
    o[8] = dc;  o[9] = 0.0f; o[10] = 0.0f; o[11] = 0.0f;
}

// One thread per (view, pixel), one block per (view, pixel-tile, face-chunk).
// Per-chunk argmin merged globally via atomicMin on sortable u64 key.
__global__ __launch_bounds__(256) void raster(
    const float* __restrict__ fd,
    unsigned long long* __restrict__ keys)
{
    __shared__ float4 lds4[CHF * 3];   // 6 KB

    int bid = blockIdx.x;
    int view  = bid >> 9;          // 512 blocks per view
    int b     = bid & 511;
    int chunk = b & (NCHUNK - 1);
    int ptile = b >> 3;            // 0..63, 256 pixels each
    int tid = threadIdx.x;

    const float4* src = (const float4*)fd + (size_t)(view * NF + chunk * CHF) * 3;
    for (int i = tid; i < CHF * 3; i += 256) lds4[i] = src[i];
    __syncthreads();

    int p = ptile * 256 + tid;
    int row = p >> 7, col = p & 127;
    float sx = ((col + 0.5f) * (1.0f / IMG)) * 2.0f - 1.0f;
    float sy = -(((row + 0.5f) * (1.0f / IMG)) * 2.0f - 1.0f);

    float best = INFINITY;
    int bf = 0;
    const float* ldsf = (const float*)lds4;

#pragma unroll 4
    for (int f = 0; f < CHF; ++f) {
        float4 Q0 = lds4[f * 3 + 0];   // a1x a1y b1 a2x
        float4 Q1 = lds4[f * 3 + 1];   // a2y b2 ddx ddy
        float dc  = ldsf[f * 12 + 8];
        float w1 = fmaf(Q0.x, sx, fmaf(Q0.y, sy, Q0.z));
        float w2 = fmaf(Q0.w, sx, fmaf(Q1.x, sy, Q1.y));
        float dep = fmaf(Q1.z, sx, fmaf(Q1.w, sy, dc));
        float s = w1 + w2;
        bool vis = (fminf(w1, w2) >= 0.0f) && (s <= 1.0f) && (dep > NEAR_Z);
        bool take = vis && (dep < best);   // strict < keeps lowest index
        best = take ? dep : best;
        bf   = take ? f : bf;
    }

    unsigned int dbits = __float_as_uint(best);   // inf -> 0x7f800000 sentinel
    unsigned long long key =
        ((unsigned long long)dbits << 32) |
        (unsigned int)(view * 0 + chunk * CHF + bf);   // view-local face id
    atomicMin(&keys[view * NPIX + p], key);
}

// One thread per (view, pixel): decode winner, trilinear tanh texture, loss.
__global__ __launch_bounds__(256) void shade_loss(
    const float* __restrict__ fd,
    const unsigned long long* __restrict__ keys,
    const float* __restrict__ tex,
    const float* __restrict__ refs,
    float* __restrict__ out)
{
    __shared__ float wsum[4];
    int t = blockIdx.x * blockDim.x + threadIdx.x;
    int view = t >> 14, p = t & (NPIX - 1);
    int row = p >> 7, col = p & 127;
    float sx = ((col + 0.5f) * (1.0f / IMG)) * 2.0f - 1.0f;
    float sy = -(((row + 0.5f) * (1.0f / IMG)) * 2.0f - 1.0f);

    unsigned long long key = keys[view * NPIX + p];
    bool hit = (unsigned int)(key >> 32) < 0x7f800000u;
    float ref = refs[t];
    float lossv;
    if (hit) {
        int f = (int)(key & 0xffffffffu);
        const float4* Q = (const float4*)fd + (size_t)(view * NF + f) * 3;
        float4 Q0 = Q[0];
        float4 Q1 = Q[1];
        float w1 = fmaf(Q0.x, sx, fmaf(Q0.y, sy, Q0.z));
        float w2 = fmaf(Q0.w, sx, fmaf(Q1.x, sy, Q1.y));
        float w0 = 1.0f - w1 - w2;
        float cx = fminf(fmaxf(w0, 0.0f), 1.0f) * 3.0f;
        float cy = fminf(fmaxf(w1, 0.0f), 1.0f) * 3.0f;
        float cz = fminf(fmaxf(w2, 0.0f), 1.0f) * 3.0f;
        int ix = min(max((int)floorf(cx), 0), 2);
        int iy = min(max((int)floorf(cy), 0), 2);
        int iz = min(max((int)floorf(cz), 0), 2);
        float fx = cx - (float)ix, fy = cy - (float)iy, fz = cz - (float)iz;

        const float* T = tex + (size_t)f * 192;   // 4*4*4*3
        float c0 = 0.0f, c1 = 0.0f, c2 = 0.0f;
        for (int dxi = 0; dxi < 2; ++dxi)
            for (int dyi = 0; dyi < 2; ++dyi)
                for (int dzi = 0; dzi < 2; ++dzi) {
                    float w = (dxi ? fx : 1.0f - fx) *
                              (dyi ? fy : 1.0f - fy) *
                              (dzi ? fz : 1.0f - fz);
                    int base = (((ix + dxi) * 4 + (iy + dyi)) * 4 + (iz + dzi)) * 3;
                    c0 += w * tanhf(T[base + 0]);
                    c1 += w * tanhf(T[base + 1]);
                    c2 += w * tanhf(T[base + 2]);
                }
        float d0 = c0 - ref, d1 = c1 - ref, d2 = c2 - ref;
        lossv = d0 * d0 + d1 * d1 + d2 * d2;
    } else {
        lossv = 3.0f * ref * ref;
    }

    for (int off = 32; off; off >>= 1) lossv += __shfl_down(lossv, off);
    int tid = threadIdx.x;
    if ((tid & 63) == 0) wsum[tid >> 6] = lossv;
    __syncthreads();
    if (tid == 0) atomicAdd(out, wsum[0] + wsum[1] + wsum[2] + wsum[3]);
}

static void make_view(double dist, double elev, double azim, float* M)
{
    double e = elev * M_PI / 180.0, a = azim * M_PI / 180.0;
    float ex = (float)(dist * cos(e) * sin(a));
    float ey = (float)(dist * sin(e));
    float ez = (float)(-dist * cos(e) * cos(a));
    float zx = -ex, zy = -ey, zz = -ez;
    float n = sqrtf(zx * zx + zy * zy + zz * zz);
    zx /= n; zy /= n; zz /= n;
    float xx = zz, xy = 0.0f, xz = -zx;
    n = sqrtf(xx * xx + xy * xy + xz * xz);
    xx /= n; xy /= n; xz /= n;
    float yx = zy * xz - zz * xy;
    float yy = zz * xx - zx * xz;
    float yz = zx * xy - zy * xx;
    n = sqrtf(yx * yx + yy * yy + yz * yz);
    yx /= n; yy /= n; yz /= n;
    M[0] = xx; M[1] = xy; M[2] = xz;
    M[3] = yx; M[4] = yy; M[5] = yz;
    M[6] = zx; M[7] = zy; M[8] = zz;
    M[9] = ex; M[10] = ey; M[11] = ez;
}

extern "C" void kernel_launch(void* const* d_in, const int* in_sizes, int n_in,
                              void* d_out, int out_size, void* d_ws, size_t ws_size,
                              hipStream_t stream)
{
    const float* verts = (const float*)d_in[0];
    const int*   faces = (const int*)d_in[1];
    const float* tex   = (const float*)d_in[2];
    const float* refs  = (const float*)d_in[3];
    float* out = (float*)d_out;

    float* fd = (float*)d_ws;                                // 192 KB
    unsigned long long* keys =
        (unsigned long long*)((char*)d_ws + 4 * NF * FSTRIDE * sizeof(float));
    // keys: 4*16384*8 = 512 KB

    AllViews vc;
    const double V[4][3] = {{2.83, 45.0, 0.0}, {2.0, 0.0, 90.0},
                            {3.46, 45.0, 45.0}, {3.0, 0.0, 0.0}};
    for (int i = 0; i < 4; ++i) make_view(V[i][0], V[i][1], V[i][2], vc.m[i]);
    float W = (float)tan(M_PI / 6.0);

    hipMemsetAsync(out, 0, sizeof(float), stream);
    hipMemsetAsync(keys, 0xFF, 4 * NPIX * sizeof(unsigned long long), stream);
    precompute_faces<<<16, 256, 0, stream>>>(verts, faces, fd, vc, W);
    raster<<<2048, 256, 0, stream>>>(fd, keys);
    shade_loss<<<256, 256, 0, stream>>>(fd, keys, tex, refs, out);
}

// Round 3
// 45.945 us; speedup vs baseline: 2.9448x; 1.0807x over previous
//
#include <hip/hip_runtime.h>
#include <math.h>

#define IMG 128
#define NPIX (IMG * IMG)
#define NF 1024
#define NCHUNK 8
#define CHF (NF / NCHUNK)          // 128 faces per chunk
#define FSTRIDE 12                 // floats per face record (3 x float4)
#define NEAR_Z 0.1f
#define NSHADE_BLK 256             // shade_loss blocks (65536 / 256)

struct AllViews { float m[4][12]; };  // per view: xax[3], yax[3], zax[3], eye[3]

// Per (view, face): transform+project vertices, build affine planes for
// w1, w2, depth as functions of screen (px, py).
__global__ void precompute_faces(const float* __restrict__ verts,
                                 const int* __restrict__ faces,
                                 float* __restrict__ fd,
                                 AllViews vc, float W)
{
    int t = blockIdx.x * blockDim.x + threadIdx.x;
    if (t >= 4 * NF) return;
    int view = t >> 10, f = t & (NF - 1);
    const float* M = vc.m[view];

    float proj[3][3];
    for (int k = 0; k < 3; ++k) {
        int vi = faces[f * 3 + k];
        float px = verts[vi * 3 + 0] - M[9];
        float py = verts[vi * 3 + 1] - M[10];
        float pz = verts[vi * 3 + 2] - M[11];
        float x = M[0] * px + M[1] * py + M[2] * pz;
        float y = M[3] * px + M[4] * py + M[5] * pz;
        float z = M[6] * px + M[7] * py + M[8] * pz;
        proj[k][0] = x / (z * W);
        proj[k][1] = y / (z * W);
        proj[k][2] = z;
    }
    float v0x = proj[0][0], v0y = proj[0][1];
    float e1x = proj[1][0] - v0x, e1y = proj[1][1] - v0y;
    float e2x = proj[2][0] - v0x, e2y = proj[2][1] - v0y;
    float det = e1x * e2y - e1y * e2x;
    bool ok = fabsf(det) > 1e-8f;
    float inv = ok ? 1.0f / det : 0.0f;

    // w1 = a1.p + b1 ; w2 = a2.p + b2 ; depth = dd.p + dc
    float a1x = e2y * inv, a1y = -e2x * inv;
    float b1 = -(a1x * v0x + a1y * v0y);
    float a2x = -e1y * inv, a2y = e1x * inv;
    float b2 = -(a2x * v0x + a2y * v0y);
    float g1 = proj[1][2] - proj[0][2];
    float g2 = proj[2][2] - proj[0][2];
    float ddx = g1 * a1x + g2 * a2x;
    float ddy = g1 * a1y + g2 * a2y;
    float dc  = proj[0][2] + g1 * b1 + g2 * b2;
    if (!ok) dc = 0.0f;   // depth 0 < NEAR -> never visible (matches `ok` mask)

    float* o = fd + (size_t)(view * NF + f) * FSTRIDE;
    o[0] = a1x; o[1] = a1y; o[2] = b1;  o[3] = a2x;
    o[4] = a2y; o[5] = b2;  o[6] = ddx; o[7] = ddy;
    o[8] = dc;  o[9] = 0.0f; o[10] = 0.0f; o[11] = 0.0f;
}

// One block per (view, pixel-tile, face-chunk). Each thread owns one pixel,
// scans its 128-face chunk, stores winner key to a private slot (no atomics).
__global__ __launch_bounds__(256) void raster(
    const float* __restrict__ fd,
    unsigned long long* __restrict__ keys)
{
    __shared__ float4 lds4[CHF * 3];   // 6 KB

    int bid = blockIdx.x;
    int view  = bid >> 9;          // 512 blocks per view
    int b     = bid & 511;
    int chunk = b & (NCHUNK - 1);
    int ptile = b >> 3;            // 0..63, 256 pixels each
    int tid = threadIdx.x;

    const float4* src = (const float4*)fd + (size_t)(view * NF + chunk * CHF) * 3;
    for (int i = tid; i < CHF * 3; i += 256) lds4[i] = src[i];
    __syncthreads();

    int p = ptile * 256 + tid;
    int row = p >> 7, col = p & 127;
    float sx = ((col + 0.5f) * (1.0f / IMG)) * 2.0f - 1.0f;
    float sy = -(((row + 0.5f) * (1.0f / IMG)) * 2.0f - 1.0f);

    float best = INFINITY;
    int bf = 0;
    const float* ldsf = (const float*)lds4;

#pragma unroll 4
    for (int f = 0; f < CHF; ++f) {
        float4 Q0 = lds4[f * 3 + 0];   // a1x a1y b1 a2x
        float4 Q1 = lds4[f * 3 + 1];   // a2y b2 ddx ddy
        float dc  = ldsf[f * 12 + 8];
        float w1 = fmaf(Q0.x, sx, fmaf(Q0.y, sy, Q0.z));
        float w2 = fmaf(Q0.w, sx, fmaf(Q1.x, sy, Q1.y));
        float dep = fmaf(Q1.z, sx, fmaf(Q1.w, sy, dc));
        float s = w1 + w2;
        bool vis = (fminf(w1, w2) >= 0.0f) && (s <= 1.0f) && (dep > NEAR_Z);
        bool take = vis && (dep < best);   // strict < keeps lowest index
        best = take ? dep : best;
        bf   = take ? f : bf;
    }

    unsigned int dbits = __float_as_uint(best);   // inf -> 0x7f800000 sentinel
    unsigned long long key =
        ((unsigned long long)dbits << 32) |
        (unsigned int)(chunk * CHF + bf);          // view-local face id
    keys[((size_t)(view * NCHUNK + chunk) << 14) + p] = key;   // private slot
}

// One thread per (view, pixel): min over 8 chunk keys, decode winner,
// trilinear tanh texture, per-block partial loss (no atomics).
__global__ __launch_bounds__(256) void shade_loss(
    const float* __restrict__ fd,
    const unsigned long long* __restrict__ keys,
    const float* __restrict__ tex,
    const float* __restrict__ refs,
    float* __restrict__ partial)
{
    __shared__ float wsum[4];
    int t = blockIdx.x * blockDim.x + threadIdx.x;
    int view = t >> 14, p = t & (NPIX - 1);
    int row = p >> 7, col = p & 127;
    float sx = ((col + 0.5f) * (1.0f / IMG)) * 2.0f - 1.0f;
    float sy = -(((row + 0.5f) * (1.0f / IMG)) * 2.0f - 1.0f);

    const unsigned long long* kb = keys + ((size_t)(view * NCHUNK) << 14) + p;
    unsigned long long key = ~0ULL;
#pragma unroll
    for (int c = 0; c < NCHUNK; ++c) {
        unsigned long long k = kb[(size_t)c << 14];
        key = (k < key) ? k : key;
    }

    bool hit = (unsigned int)(key >> 32) < 0x7f800000u;
    float ref = refs[t];
    float lossv;
    if (hit) {
        int f = (int)(key & 0xffffffffu);
        const float4* Q = (const float4*)fd + (size_t)(view * NF + f) * 3;
        float4 Q0 = Q[0];
        float4 Q1 = Q[1];
        float w1 = fmaf(Q0.x, sx, fmaf(Q0.y, sy, Q0.z));
        float w2 = fmaf(Q0.w, sx, fmaf(Q1.x, sy, Q1.y));
        float w0 = 1.0f - w1 - w2;
        float cx = fminf(fmaxf(w0, 0.0f), 1.0f) * 3.0f;
        float cy = fminf(fmaxf(w1, 0.0f), 1.0f) * 3.0f;
        float cz = fminf(fmaxf(w2, 0.0f), 1.0f) * 3.0f;
        int ix = min(max((int)floorf(cx), 0), 2);
        int iy = min(max((int)floorf(cy), 0), 2);
        int iz = min(max((int)floorf(cz), 0), 2);
        float fx = cx - (float)ix, fy = cy - (float)iy, fz = cz - (float)iz;

        const float* T = tex + (size_t)f * 192;   // 4*4*4*3
        float c0 = 0.0f, c1 = 0.0f, c2 = 0.0f;
        for (int dxi = 0; dxi < 2; ++dxi)
            for (int dyi = 0; dyi < 2; ++dyi)
                for (int dzi = 0; dzi < 2; ++dzi) {
                    float w = (dxi ? fx : 1.0f - fx) *
                              (dyi ? fy : 1.0f - fy) *
                              (dzi ? fz : 1.0f - fz);
                    int base = (((ix + dxi) * 4 + (iy + dyi)) * 4 + (iz + dzi)) * 3;
                    c0 += w * tanhf(T[base + 0]);
                    c1 += w * tanhf(T[base + 1]);
                    c2 += w * tanhf(T[base + 2]);
                }
        float d0 = c0 - ref, d1 = c1 - ref, d2 = c2 - ref;
        lossv = d0 * d0 + d1 * d1 + d2 * d2;
    } else {
        lossv = 3.0f * ref * ref;
    }

    for (int off = 32; off; off >>= 1) lossv += __shfl_down(lossv, off);
    int tid = threadIdx.x;
    if ((tid & 63) == 0) wsum[tid >> 6] = lossv;
    __syncthreads();
    if (tid == 0) partial[blockIdx.x] = wsum[0] + wsum[1] + wsum[2] + wsum[3];
}

// Single block: sum NSHADE_BLK partials, plain-store the scalar loss.
__global__ __launch_bounds__(256) void final_reduce(
    const float* __restrict__ partial, float* __restrict__ out)
{
    __shared__ float wsum[4];
    int tid = threadIdx.x;
    float v = partial[tid];
    for (int off = 32; off; off >>= 1) v += __shfl_down(v, off);
    if ((tid & 63) == 0) wsum[tid >> 6] = v;
    __syncthreads();
    if (tid == 0) out[0] = wsum[0] + wsum[1] + wsum[2] + wsum[3];
}

static void make_view(double dist, double elev, double azim, float* M)
{
    double e = elev * M_PI / 180.0, a = azim * M_PI / 180.0;
    float ex = (float)(dist * cos(e) * sin(a));
    float ey = (float)(dist * sin(e));
    float ez = (float)(-dist * cos(e) * cos(a));
    float zx = -ex, zy = -ey, zz = -ez;
    float n = sqrtf(zx * zx + zy * zy + zz * zz);
    zx /= n; zy /= n; zz /= n;
    float xx = zz, xy = 0.0f, xz = -zx;
    n = sqrtf(xx * xx + xy * xy + xz * xz);
    xx /= n; xy /= n; xz /= n;
    float yx = zy * xz - zz * xy;
    float yy = zz * xx - zx * xz;
    float yz = zx * xy - zy * xx;
    n = sqrtf(yx * yx + yy * yy + yz * yz);
    yx /= n; yy /= n; yz /= n;
    M[0] = xx; M[1] = xy; M[2] = xz;
    M[3] = yx; M[4] = yy; M[5] = yz;
    M[6] = zx; M[7] = zy; M[8] = zz;
    M[9] = ex; M[10] = ey; M[11] = ez;
}

extern "C" void kernel_launch(void* const* d_in, const int* in_sizes, int n_in,
                              void* d_out, int out_size, void* d_ws, size_t ws_size,
                              hipStream_t stream)
{
    const float* verts = (const float*)d_in[0];
    const int*   faces = (const int*)d_in[1];
    const float* tex   = (const float*)d_in[2];
    const float* refs  = (const float*)d_in[3];
    float* out = (float*)d_out;

    char* ws = (char*)d_ws;
    float* fd = (float*)ws;                       // 4*1024*12*4   = 192 KB
    ws += 4 * NF * FSTRIDE * sizeof(float);
    unsigned long long* keys = (unsigned long long*)ws;  // 4*8*16384*8 = 4 MB
    ws += (size_t)4 * NCHUNK * NPIX * sizeof(unsigned long long);
    float* partial = (float*)ws;                  // 256 floats = 1 KB

    AllViews vc;
    const double V[4][3] = {{2.83, 45.0, 0.0}, {2.0, 0.0, 90.0},
                            {3.46, 45.0, 45.0}, {3.0, 0.0, 0.0}};
    for (int i = 0; i < 4; ++i) make_view(V[i][0], V[i][1], V[i][2], vc.m[i]);
    float W = (float)tan(M_PI / 6.0);

    precompute_faces<<<16, 256, 0, stream>>>(verts, faces, fd, vc, W);
    raster<<<2048, 256, 0, stream>>>(fd, keys);
    shade_loss<<<NSHADE_BLK, 256, 0, stream>>>(fd, keys, tex, refs, partial);
    final_reduce<<<1, 256, 0, stream>>>(partial, out);
}